// Round 11
// baseline (224.031 us; speedup 1.0000x reference)
//
#include <hip/hip_runtime.h>
#include <hip/hip_bf16.h>
#include <hip/hip_fp16.h>
#include <cstdint>
#include <cstddef>

typedef __bf16 bf16;
typedef __attribute__((ext_vector_type(8))) __bf16 bf16x8;
typedef __attribute__((ext_vector_type(16))) float f32x16;

static_assert(sizeof(bf16x8) == 16, "bf16x8 must be 16B");

#define NTASK 34
#define BTOT 16384
#define WSTRIDE 73728   // bf16 elems per task: A-part 36864 (72KB), B-part 36864 (72KB)

__device__ __forceinline__ f32x16 mfma32(bf16x8 a, bf16x8 b, f32x16 c) {
  return __builtin_amdgcn_mfma_f32_32x32x16_bf16(a, b, c, 0, 0, 0);
}

__device__ __forceinline__ void gload_lds16(const void* g, void* l) {
  __builtin_amdgcn_global_load_lds((__attribute__((address_space(1))) void*)g,
                                   (__attribute__((address_space(3))) void*)l,
                                   16, 0, 0);
}

__device__ __forceinline__ unsigned pack2(float lo, float hi) {
  union { __bf16 h[2]; unsigned u; } v;
  v.h[0] = (__bf16)lo; v.h[1] = (__bf16)hi;
  return v.u;
}

__device__ __forceinline__ void pl32swap(unsigned &a, unsigned &b) {
  asm volatile("v_permlane32_swap_b32 %0, %1" : "+v"(a), "+v"(b));
}

// ---------------- prep (merged) ----------------
// blocks [0,1190): weights -> 32x32 A-frag blocks (1KB), per-task stream.
//   A-part (elems [0,36864)):  W1 blocks mt*17+ks (ks=16 bias row), 68KB + 4KB pad
//   B-part (elems [36864,73728)): W2 blocks mt*9+ks, then W3 blocks at +18432
// blocks [1190,3238): state -> 32x32 B-frag blocks.
__global__ void prep_all(const float* __restrict__ W1, const float* __restrict__ W2,
                         const float* __restrict__ W3, const float* __restrict__ b1,
                         const float* __restrict__ b2, const float* __restrict__ b3,
                         const float* __restrict__ state,
                         bf16* __restrict__ wdst, bf16* __restrict__ sdst) {
  int bid = blockIdx.x;
  if (bid < 1190) {
    int idx = bid * 256 + threadIdx.x;    // 34*140*64 = 304640
    if (idx >= 304640) return;
    int n = idx / (140 * 64);
    int r = idx - n * (140 * 64);
    int bb = r >> 6, l = r & 63;
    const float *W, *bias; int real, mt, ks, Kt;
    size_t off;
    if (bb < 68)       { W = W1; bias = b1; mt = bb / 17; ks = bb - mt * 17; real = 16; Kt = 256;
                         off = (size_t)bb * 512; }
    else if (bb < 104) { W = W2; bias = b2; int t = bb - 68;  mt = t / 9; ks = t - mt * 9; real = 8; Kt = 128;
                         off = 36864 + (size_t)(bb - 68) * 512; }
    else               { W = W3; bias = b3; int t = bb - 104; mt = t / 9; ks = t - mt * 9; real = 8; Kt = 128;
                         off = 36864 + 18432 + (size_t)(bb - 104) * 512; }
    int col = mt * 32 + (l & 31);
    bf16x8 v;
    if (ks < real) {
      int k0 = ks * 16 + ((l >> 5) << 3);
      const float* s = W + ((size_t)n * Kt + k0) * 128 + col;
#pragma unroll
      for (int j = 0; j < 8; ++j) v[j] = (bf16)s[(size_t)j * 128];
    } else {
#pragma unroll
      for (int j = 0; j < 8; ++j) v[j] = (bf16)0.f;
      if (l < 32) v[0] = (bf16)bias[n * 128 + col];
    }
    *(bf16x8*)(wdst + (size_t)n * WSTRIDE + off + l * 8) = v;
  } else {
    int idx = (bid - 1190) * 256 + threadIdx.x;   // 524288 exact
    int rb = idx >> 10;
    int r = idx & 1023;
    int ks = r >> 6;
    int l = r & 63;
    int b = rb * 32 + (l & 31);
    int k0 = ks * 16 + ((l >> 5) << 3);
    const float* s = state + (size_t)b * 256 + k0;
    bf16x8 v;
#pragma unroll
    for (int j = 0; j < 8; ++j) v[j] = (bf16)s[j];
    *(bf16x8*)(sdst + (size_t)(rb * 16 + ks) * 512 + l * 8) = v;
  }
}

__global__ void prep_langn(const float* __restrict__ lang, float* __restrict__ out) {
  __shared__ float red[2];
  int n = blockIdx.x;
  int t = threadIdx.x;                        // 128 threads
  float v = lang[(size_t)n * 128 + t];
  float ss = v * v;
#pragma unroll
  for (int m = 1; m < 64; m <<= 1) ss += __shfl_xor(ss, m);
  if ((t & 63) == 0) red[t >> 6] = ss;
  __syncthreads();
  float s = red[0] + red[1];
  float sc = 1.0f / fmaxf(sqrtf(s), 1e-8f);
  out[(size_t)n * 128 + t] = v * sc;
}

// softmax(prior) -> f32 transposed pp_t[34][B]
__global__ void prep_pprior(const float* __restrict__ prior, float* __restrict__ ppt) {
  int row = blockIdx.x * 4 + (threadIdx.x >> 6);
  int lane = threadIdx.x & 63;
  float v = (lane < NTASK) ? prior[(size_t)row * NTASK + lane] : -INFINITY;
  float m = v;
#pragma unroll
  for (int mm = 1; mm < 64; mm <<= 1) m = fmaxf(m, __shfl_xor(m, mm));
  float e = (lane < NTASK) ? expf(v - m) : 0.0f;
  float s = e;
#pragma unroll
  for (int mm = 1; mm < 64; mm <<= 1) s += __shfl_xor(s, mm);
  if (lane < NTASK) ppt[(size_t)lane * BTOT + row] = e / s;
}

// ---------------- pass 1: task-fused, latent in packed-f16 registers ----------------
// grid = 256: bid = tg*32 + rg. Block = 8 waves x 64 rows = 512 rows, 512 thr,
// launch_bounds(512,2) -> 2 waves/SIMD, 256 regs/wave. LDS 144KB (A 72 + B 72),
// cross-task pipelined staging (9x8KB issues per phase). Latent via v_pk_fma_f16.

__global__ void __launch_bounds__(512, 2)
pass1_kernel(const int* __restrict__ task_id, const bf16* __restrict__ wstream,
             const bf16* __restrict__ sf, const float* __restrict__ langn,
             const float* __restrict__ pp_t,
             float* __restrict__ cs_t, __half* __restrict__ lat_part,
             float* __restrict__ out_tgt) {
  __shared__ __align__(16) bf16 shA[36864];   // 72KB: W1+bias frags (+pad)
  __shared__ __align__(16) bf16 shB[36864];   // 72KB: W2+W3 frags

  const int tid = threadIdx.x;
  const int l = tid & 63;
  const int w = tid >> 6;          // wave 0..7
  const int hi = l >> 5;
  const int b = l & 31;
  const int tg = blockIdx.x >> 5;  // task group 0..7
  const int rg = blockIdx.x & 31;  // 512-row group
  const int start = tg * 4 + (tg < 2 ? tg : 2);   // 0,5,10,14,18,22,26,30
  const int cnt = 4 + (tg < 2 ? 1 : 0);           // 5,5,4,4,4,4,4,4
  const int rowbase = rg * 512 + w * 64;
  const int row0 = rowbase + b;    // tile0 row (tile1 = +32)
  const int rb0 = rg * 16 + w * 2; // 32-row frag-block index tile0

  int tidn0 = task_id[row0];
  int tidn1 = task_id[row0 + 32];

  // prologue: stage A(start): 9 x 8KB
  {
    const bf16* wb0 = wstream + (size_t)start * WSTRIDE;
#pragma unroll
    for (int c = 0; c < 9; ++c)
      gload_lds16(wb0 + c * 4096 + tid * 8, shA + c * 4096 + tid * 8);
  }

  // const "1" B-frag for the bias K-augment step
  union { unsigned u[4]; bf16x8 v; } cf;
  cf.u[0] = (l < 32) ? 0x3f80u : 0u;
  cf.u[1] = 0u; cf.u[2] = 0u; cf.u[3] = 0u;

  f32x16 z;
#pragma unroll
  for (int i = 0; i < 16; ++i) z[i] = 0.f;

  const __half2 hz = __float2half2_rn(0.0f);
  __half2 lat0[4][4][2], lat1[4][4][2];
#pragma unroll
  for (int mt = 0; mt < 4; ++mt)
#pragma unroll
    for (int q = 0; q < 4; ++q) {
      lat0[mt][q][0] = hz; lat0[mt][q][1] = hz;
      lat1[mt][q][0] = hz; lat1[mt][q][1] = hz;
    }

  const bf16* sb0 = sf + (size_t)rb0 * 8192 + l * 8;
  const bf16* sb1 = sb0 + 8192;

  auto transition = [&](f32x16* acc, bf16x8* f) {
#pragma unroll
    for (int mt = 0; mt < 4; ++mt) {
      unsigned p[8];
#pragma unroll
      for (int q = 0; q < 4; ++q) {
        p[2 * q]     = pack2(fmaxf(acc[mt][4 * q + 0], 0.f), fmaxf(acc[mt][4 * q + 1], 0.f));
        p[2 * q + 1] = pack2(fmaxf(acc[mt][4 * q + 2], 0.f), fmaxf(acc[mt][4 * q + 3], 0.f));
      }
      pl32swap(p[0], p[2]); pl32swap(p[1], p[3]);
      pl32swap(p[4], p[6]); pl32swap(p[5], p[7]);
      union { unsigned u[4]; bf16x8 v; } e, o;
      e.u[0] = p[0]; e.u[1] = p[1]; e.u[2] = p[2]; e.u[3] = p[3];
      o.u[0] = p[4]; o.u[1] = p[5]; o.u[2] = p[6]; o.u[3] = p[7];
      f[2 * mt] = e.v; f[2 * mt + 1] = o.v;
    }
  };

  for (int t = 0; t < cnt; ++t) {
    const int n = start + t;
    const bf16* wbase = wstream + (size_t)n * WSTRIDE;

    // stage B(n): W2/W3, 9 x 8KB (shB free: fenced by previous post-G3 barrier)
#pragma unroll
    for (int c = 0; c < 9; ++c)
      gload_lds16(wbase + 36864 + c * 4096 + tid * 8, shB + c * 4096 + tid * 8);

    if (t == 0) {   // wait A(start): the 9 B-ops are younger
      asm volatile("s_waitcnt vmcnt(9)" ::: "memory");
      __builtin_amdgcn_s_barrier();
    }

    f32x16 acc0[4] = {z, z, z, z};
    f32x16 acc1[4] = {z, z, z, z};

    // ---- GEMM1 from shA: 16 data ksteps + const kstep
    bf16x8 s0[4], s1[4];
#pragma unroll
    for (int i = 0; i < 4; ++i) {
      s0[i] = *(const bf16x8*)(sb0 + i * 512);
      s1[i] = *(const bf16x8*)(sb1 + i * 512);
    }
#pragma unroll
    for (int ks = 0; ks < 16; ++ks) {
      bf16x8 sv0 = s0[ks & 3], sv1 = s1[ks & 3];
      if (ks < 12) {
        s0[ks & 3] = *(const bf16x8*)(sb0 + (ks + 4) * 512);
        s1[ks & 3] = *(const bf16x8*)(sb1 + (ks + 4) * 512);
      }
      __builtin_amdgcn_s_setprio(1);
#pragma unroll
      for (int mt = 0; mt < 4; ++mt) {
        bf16x8 wf = *(const bf16x8*)(shA + ((mt * 17 + ks) << 9) + l * 8);
        acc0[mt] = mfma32(wf, sv0, acc0[mt]);
        acc1[mt] = mfma32(wf, sv1, acc1[mt]);
      }
      __builtin_amdgcn_s_setprio(0);
    }
#pragma unroll
    for (int mt = 0; mt < 4; ++mt) {
      bf16x8 wf = *(const bf16x8*)(shA + ((mt * 17 + 16) << 9) + l * 8);
      acc0[mt] = mfma32(wf, cf.v, acc0[mt]);
      acc1[mt] = mfma32(wf, cf.v, acc1[mt]);
    }

    bf16x8 f2a[8], f2b[8];
    transition(acc0, f2a);
    transition(acc1, f2b);

    asm volatile("s_waitcnt vmcnt(0)" ::: "memory");  // B(n) landed
    __builtin_amdgcn_s_barrier();                      // + WAR fence for A restage

    // ---- GEMM2 from shB; stage A(t+1) under it
    if (t + 1 < cnt) {
      const bf16* wnext = wstream + (size_t)(n + 1) * WSTRIDE;
#pragma unroll
      for (int c = 0; c < 9; ++c)
        gload_lds16(wnext + c * 4096 + tid * 8, shA + c * 4096 + tid * 8);
    }
#pragma unroll
    for (int mt = 0; mt < 4; ++mt) { acc0[mt] = z; acc1[mt] = z; }
#pragma unroll
    for (int ks = 0; ks < 8; ++ks) {
      __builtin_amdgcn_s_setprio(1);
#pragma unroll
      for (int mt = 0; mt < 4; ++mt) {
        bf16x8 wf = *(const bf16x8*)(shB + ((mt * 9 + ks) << 9) + l * 8);
        acc0[mt] = mfma32(wf, f2a[ks], acc0[mt]);
        acc1[mt] = mfma32(wf, f2b[ks], acc1[mt]);
      }
      __builtin_amdgcn_s_setprio(0);
    }
#pragma unroll
    for (int mt = 0; mt < 4; ++mt) {
      bf16x8 wf = *(const bf16x8*)(shB + ((mt * 9 + 8) << 9) + l * 8);
      acc0[mt] = mfma32(wf, cf.v, acc0[mt]);
      acc1[mt] = mfma32(wf, cf.v, acc1[mt]);
    }

    bf16x8 f3a[8], f3b[8];
    transition(acc0, f3a);
    transition(acc1, f3b);

    // ---- GEMM3 from shB
#pragma unroll
    for (int mt = 0; mt < 4; ++mt) { acc0[mt] = z; acc1[mt] = z; }
#pragma unroll
    for (int ks = 0; ks < 8; ++ks) {
      __builtin_amdgcn_s_setprio(1);
#pragma unroll
      for (int mt = 0; mt < 4; ++mt) {
        bf16x8 wf = *(const bf16x8*)(shB + ((36 + mt * 9 + ks) << 9) + l * 8);
        acc0[mt] = mfma32(wf, f3a[ks], acc0[mt]);
        acc1[mt] = mfma32(wf, f3b[ks], acc1[mt]);
      }
      __builtin_amdgcn_s_setprio(0);
    }
#pragma unroll
    for (int mt = 0; mt < 4; ++mt) {
      bf16x8 wf = *(const bf16x8*)(shB + ((36 + mt * 9 + 8) << 9) + l * 8);
      acc0[mt] = mfma32(wf, cf.v, acc0[mt]);
      acc1[mt] = mfma32(wf, cf.v, acc1[mt]);
    }

    asm volatile("s_waitcnt vmcnt(0)" ::: "memory");  // A(t+1) landed
    __builtin_amdgcn_s_barrier();                      // + WAR fence for B restage

    // ---- epilogue: ssq/dot, cs, tgt, latent f16 pk-fma accumulation
    float ssq0 = 0.f, dot0 = 0.f, ssq1 = 0.f, dot1 = 0.f;
    const float* lg0b = langn + (size_t)tidn0 * 128;
    const float* lg1b = langn + (size_t)tidn1 * 128;
#pragma unroll
    for (int mt = 0; mt < 4; ++mt)
#pragma unroll
      for (int q = 0; q < 4; ++q) {
        int c0 = mt * 32 + q * 8 + 4 * hi;
        float4 lg0 = *(const float4*)(lg0b + c0);
        float4 lg1 = *(const float4*)(lg1b + c0);
        float a0 = acc0[mt][4 * q + 0], a1 = acc0[mt][4 * q + 1];
        float a2 = acc0[mt][4 * q + 2], a3 = acc0[mt][4 * q + 3];
        ssq0 += a0 * a0 + a1 * a1 + a2 * a2 + a3 * a3;
        dot0 += a0 * lg0.x + a1 * lg0.y + a2 * lg0.z + a3 * lg0.w;
        float c1 = acc1[mt][4 * q + 0], c2 = acc1[mt][4 * q + 1];
        float c3 = acc1[mt][4 * q + 2], c4 = acc1[mt][4 * q + 3];
        ssq1 += c1 * c1 + c2 * c2 + c3 * c3 + c4 * c4;
        dot1 += c1 * lg1.x + c2 * lg1.y + c3 * lg1.z + c4 * lg1.w;
      }
    ssq0 += __shfl_xor(ssq0, 32); dot0 += __shfl_xor(dot0, 32);
    ssq1 += __shfl_xor(ssq1, 32); dot1 += __shfl_xor(dot1, 32);
    float inv0 = rsqrtf(ssq0), inv1 = rsqrtf(ssq1);
    if (l < 32) {
      cs_t[(size_t)row0 * NTASK + n] = dot0 * inv0;
      cs_t[(size_t)(row0 + 32) * NTASK + n] = dot1 * inv1;
    }
    // latent += pp * inv * q  (packed f16 fma; 2 cols per op)
    float pwi0 = pp_t[(size_t)n * BTOT + row0] * inv0;
    float pwi1 = pp_t[(size_t)n * BTOT + row0 + 32] * inv1;
    __half2 pw0 = __float2half2_rn(pwi0);
    __half2 pw1 = __float2half2_rn(pwi1);
#pragma unroll
    for (int mt = 0; mt < 4; ++mt)
#pragma unroll
      for (int q = 0; q < 4; ++q) {
        lat0[mt][q][0] = __hfma2(__floats2half2_rn(acc0[mt][4 * q + 0], acc0[mt][4 * q + 1]), pw0, lat0[mt][q][0]);
        lat0[mt][q][1] = __hfma2(__floats2half2_rn(acc0[mt][4 * q + 2], acc0[mt][4 * q + 3]), pw0, lat0[mt][q][1]);
        lat1[mt][q][0] = __hfma2(__floats2half2_rn(acc1[mt][4 * q + 0], acc1[mt][4 * q + 1]), pw1, lat1[mt][q][0]);
        lat1[mt][q][1] = __hfma2(__floats2half2_rn(acc1[mt][4 * q + 2], acc1[mt][4 * q + 3]), pw1, lat1[mt][q][1]);
      }
    // latent_target (unique writer)
    if (tidn0 == n) {
#pragma unroll
      for (int mt = 0; mt < 4; ++mt)
#pragma unroll
        for (int q = 0; q < 4; ++q) {
          float4 qv = {acc0[mt][4 * q + 0] * inv0, acc0[mt][4 * q + 1] * inv0,
                       acc0[mt][4 * q + 2] * inv0, acc0[mt][4 * q + 3] * inv0};
          *(float4*)(out_tgt + (size_t)row0 * 128 + mt * 32 + q * 8 + 4 * hi) = qv;
        }
    }
    if (tidn1 == n) {
#pragma unroll
      for (int mt = 0; mt < 4; ++mt)
#pragma unroll
        for (int q = 0; q < 4; ++q) {
          float4 qv = {acc1[mt][4 * q + 0] * inv1, acc1[mt][4 * q + 1] * inv1,
                       acc1[mt][4 * q + 2] * inv1, acc1[mt][4 * q + 3] * inv1};
          *(float4*)(out_tgt + (size_t)(row0 + 32) * 128 + mt * 32 + q * 8 + 4 * hi) = qv;
        }
    }
  }

  // ---- write f16 partial latent for this task group: lat_part[tg][row][128]
  __half* lp0 = lat_part + ((size_t)tg * BTOT + row0) * 128;
  __half* lp1 = lat_part + ((size_t)tg * BTOT + row0 + 32) * 128;
#pragma unroll
  for (int mt = 0; mt < 4; ++mt)
#pragma unroll
    for (int q = 0; q < 4; ++q) {
      int c0 = mt * 32 + q * 8 + 4 * hi;
      union { __half2 h[2]; uint2 u; } v0, v1;
      v0.h[0] = lat0[mt][q][0]; v0.h[1] = lat0[mt][q][1];
      v1.h[0] = lat1[mt][q][0]; v1.h[1] = lat1[mt][q][1];
      *(uint2*)(lp0 + c0) = v0.u;
      *(uint2*)(lp1 + c0) = v1.u;
    }
}

// ---------------- pass 3: per-row combine (1 wave per row) ----------------

__global__ void __launch_bounds__(256)
pass3_kernel(const float* __restrict__ state, const float* __restrict__ cs_t,
             const __half* __restrict__ lat_part,
             float* __restrict__ out_rep, float* __restrict__ out_ltp,
             float* __restrict__ out_lat) {
  int w = threadIdx.x >> 6, l = threadIdx.x & 63;
  size_t row = (size_t)blockIdx.x * 4 + w;

  // log_softmax(cos*10)
  float c = (l < NTASK) ? cs_t[row * NTASK + l] * 10.0f : -1e30f;
  float cm = c;
#pragma unroll
  for (int mm = 1; mm < 64; mm <<= 1) cm = fmaxf(cm, __shfl_xor(cm, mm));
  float ce = (l < NTASK) ? expf(c - cm) : 0.0f;
  float cs = ce;
#pragma unroll
  for (int mm = 1; mm < 64; mm <<= 1) cs += __shfl_xor(cs, mm);
  if (l < NTASK) out_ltp[row * NTASK + l] = c - cm - logf(cs);

  // latent = sum of 8 f16 task-group partials; lane covers cols {2l, 2l+1}
  float2 lv = {0.f, 0.f};
#pragma unroll
  for (int g = 0; g < 8; ++g) {
    __half2 p = *(const __half2*)(lat_part + ((size_t)g * BTOT + row) * 128 + 2 * l);
    lv.x += __low2float(p);
    lv.y += __high2float(p);
  }
  *(float2*)(out_lat + row * 128 + 2 * l) = lv;
  *(float2*)(out_rep + row * 384 + 256 + 2 * l) = lv;

  // state passthrough
  float4 sv = *(const float4*)(state + row * 256 + l * 4);
  *(float4*)(out_rep + row * 384 + l * 4) = sv;
}

// ---------------- launch ----------------

extern "C" void kernel_launch(void* const* d_in, const int* in_sizes, int n_in,
                              void* d_out, int out_size, void* d_ws, size_t ws_size,
                              hipStream_t stream) {
  (void)in_sizes; (void)n_in; (void)out_size; (void)ws_size;
  const float* state = (const float*)d_in[0];
  const int* task_id = (const int*)d_in[1];
  const float* prior = (const float*)d_in[2];
  const float* W1 = (const float*)d_in[3];
  const float* b1 = (const float*)d_in[4];
  const float* W2 = (const float*)d_in[5];
  const float* b2 = (const float*)d_in[6];
  const float* W3 = (const float*)d_in[7];
  const float* b3 = (const float*)d_in[8];
  const float* lang = (const float*)d_in[9];

  char* ws = (char*)d_ws;
  bf16* wstream  = (bf16*)(ws + 0);           //  5,013,504 B (34 x 144KB)
  bf16* sf       = (bf16*)(ws + 5013504);     //  8,388,608 B
  float* langn   = (float*)(ws + 13402112);   //     17,408 B
  float* pp_t    = (float*)(ws + 13419520);   //  2,228,224 B [34][16384]
  float* cs_t    = (float*)(ws + 15647744);   //  2,228,224 B [16384][34]
  __half* lat_part = (__half*)(ws + 17875968);// 33,554,432 B [8][16384][128] f16
                                              // total 51,430,400 B

  float* out = (float*)d_out;
  float* out_rep = out;                 // [B,384]
  float* out_ltp = out + 6291456;       // [B,34]
  float* out_tgt = out + 6848512;       // [B,128]
  float* out_lat = out + 8945664;       // [B,128]

  prep_all<<<3238, 256, 0, stream>>>(W1, W2, W3, b1, b2, b3, state, wstream, sf);
  prep_langn<<<NTASK, 128, 0, stream>>>(lang, langn);
  prep_pprior<<<4096, 256, 0, stream>>>(prior, pp_t);
  pass1_kernel<<<256, 512, 0, stream>>>(task_id, wstream, sf, langn, pp_t,
                                        cs_t, lat_part, out_tgt);
  pass3_kernel<<<4096, 256, 0, stream>>>(state, cs_t, lat_part,
                                         out_rep, out_ltp, out_lat);
}

// Round 12
// 160.682 us; speedup vs baseline: 1.3942x; 1.3942x over previous
//
#include <hip/hip_runtime.h>
#include <hip/hip_bf16.h>
#include <hip/hip_fp16.h>
#include <cstdint>
#include <cstddef>

typedef __bf16 bf16;
typedef __attribute__((ext_vector_type(8))) __bf16 bf16x8;
typedef __attribute__((ext_vector_type(16))) float f32x16;

static_assert(sizeof(bf16x8) == 16, "bf16x8 must be 16B");

#define NTASK 34
#define BTOT 16384
#define WSTRIDE 73728   // bf16 elems per task: A-part 36864 (72KB), B-part 36864 (72KB)

__device__ __forceinline__ f32x16 mfma32(bf16x8 a, bf16x8 b, f32x16 c) {
  return __builtin_amdgcn_mfma_f32_32x32x16_bf16(a, b, c, 0, 0, 0);
}

__device__ __forceinline__ void gload_lds16(const void* g, void* l) {
  __builtin_amdgcn_global_load_lds((__attribute__((address_space(1))) void*)g,
                                   (__attribute__((address_space(3))) void*)l,
                                   16, 0, 0);
}

__device__ __forceinline__ unsigned pack2(float lo, float hi) {
  union { __bf16 h[2]; unsigned u; } v;
  v.h[0] = (__bf16)lo; v.h[1] = (__bf16)hi;
  return v.u;
}

__device__ __forceinline__ void pl32swap(unsigned &a, unsigned &b) {
  asm volatile("v_permlane32_swap_b32 %0, %1" : "+v"(a), "+v"(b));
}

// ---------------- prep (merged) ----------------
// blocks [0,1190): weights -> 32x32 A-frag blocks (1KB), per-task stream.
//   A-part (elems [0,36864)):  W1 blocks mt*17+ks (ks=16 bias row), 68KB + 4KB pad
//   B-part (elems [36864,73728)): W2 blocks mt*9+ks, then W3 blocks at +18432
// blocks [1190,3238): state -> 32x32 B-frag blocks.
__global__ void prep_all(const float* __restrict__ W1, const float* __restrict__ W2,
                         const float* __restrict__ W3, const float* __restrict__ b1,
                         const float* __restrict__ b2, const float* __restrict__ b3,
                         const float* __restrict__ state,
                         bf16* __restrict__ wdst, bf16* __restrict__ sdst) {
  int bid = blockIdx.x;
  if (bid < 1190) {
    int idx = bid * 256 + threadIdx.x;    // 34*140*64 = 304640
    if (idx >= 304640) return;
    int n = idx / (140 * 64);
    int r = idx - n * (140 * 64);
    int bb = r >> 6, l = r & 63;
    const float *W, *bias; int real, mt, ks, Kt;
    size_t off;
    if (bb < 68)       { W = W1; bias = b1; mt = bb / 17; ks = bb - mt * 17; real = 16; Kt = 256;
                         off = (size_t)bb * 512; }
    else if (bb < 104) { W = W2; bias = b2; int t = bb - 68;  mt = t / 9; ks = t - mt * 9; real = 8; Kt = 128;
                         off = 36864 + (size_t)(bb - 68) * 512; }
    else               { W = W3; bias = b3; int t = bb - 104; mt = t / 9; ks = t - mt * 9; real = 8; Kt = 128;
                         off = 36864 + 18432 + (size_t)(bb - 104) * 512; }
    int col = mt * 32 + (l & 31);
    bf16x8 v;
    if (ks < real) {
      int k0 = ks * 16 + ((l >> 5) << 3);
      const float* s = W + ((size_t)n * Kt + k0) * 128 + col;
#pragma unroll
      for (int j = 0; j < 8; ++j) v[j] = (bf16)s[(size_t)j * 128];
    } else {
#pragma unroll
      for (int j = 0; j < 8; ++j) v[j] = (bf16)0.f;
      if (l < 32) v[0] = (bf16)bias[n * 128 + col];
    }
    *(bf16x8*)(wdst + (size_t)n * WSTRIDE + off + l * 8) = v;
  } else {
    int idx = (bid - 1190) * 256 + threadIdx.x;   // 524288 exact
    int rb = idx >> 10;
    int r = idx & 1023;
    int ks = r >> 6;
    int l = r & 63;
    int b = rb * 32 + (l & 31);
    int k0 = ks * 16 + ((l >> 5) << 3);
    const float* s = state + (size_t)b * 256 + k0;
    bf16x8 v;
#pragma unroll
    for (int j = 0; j < 8; ++j) v[j] = (bf16)s[j];
    *(bf16x8*)(sdst + (size_t)(rb * 16 + ks) * 512 + l * 8) = v;
  }
}

__global__ void prep_langn(const float* __restrict__ lang, float* __restrict__ out) {
  __shared__ float red[2];
  int n = blockIdx.x;
  int t = threadIdx.x;                        // 128 threads
  float v = lang[(size_t)n * 128 + t];
  float ss = v * v;
#pragma unroll
  for (int m = 1; m < 64; m <<= 1) ss += __shfl_xor(ss, m);
  if ((t & 63) == 0) red[t >> 6] = ss;
  __syncthreads();
  float s = red[0] + red[1];
  float sc = 1.0f / fmaxf(sqrtf(s), 1e-8f);
  out[(size_t)n * 128 + t] = v * sc;
}

// softmax(prior) -> f32 transposed pp_t[34][B]
__global__ void prep_pprior(const float* __restrict__ prior, float* __restrict__ ppt) {
  int row = blockIdx.x * 4 + (threadIdx.x >> 6);
  int lane = threadIdx.x & 63;
  float v = (lane < NTASK) ? prior[(size_t)row * NTASK + lane] : -INFINITY;
  float m = v;
#pragma unroll
  for (int mm = 1; mm < 64; mm <<= 1) m = fmaxf(m, __shfl_xor(m, mm));
  float e = (lane < NTASK) ? expf(v - m) : 0.0f;
  float s = e;
#pragma unroll
  for (int mm = 1; mm < 64; mm <<= 1) s += __shfl_xor(s, mm);
  if (lane < NTASK) ppt[(size_t)lane * BTOT + row] = e / s;
}

// ---------------- pass 1: task-fused, 32 rows/wave, latent f32 in regs ----------------
// grid = 512: bid = tg*64 + rg. Block = 8 waves x 32 rows = 256 rows, 512 thr,
// launch_bounds(512,2) -> 2 waves/SIMD, 256 regs/wave (acc 64 + lat 64 fits).
// LDS 144KB (A 72 + B 72), cross-task pipelined staging (9x8KB per phase).

__global__ void __launch_bounds__(512, 2)
pass1_kernel(const int* __restrict__ task_id, const bf16* __restrict__ wstream,
             const bf16* __restrict__ sf, const float* __restrict__ langn,
             const float* __restrict__ pp_t,
             float* __restrict__ cs_t, __half* __restrict__ lat_part,
             float* __restrict__ out_tgt) {
  __shared__ __align__(16) bf16 shA[36864];   // 72KB: W1+bias frags (+pad)
  __shared__ __align__(16) bf16 shB[36864];   // 72KB: W2+W3 frags

  const int tid = threadIdx.x;
  const int l = tid & 63;
  const int w = tid >> 6;          // wave 0..7
  const int hi = l >> 5;
  const int b = l & 31;
  const int tg = blockIdx.x >> 6;  // task group 0..7
  const int rg = blockIdx.x & 63;  // 256-row group
  const int start = tg * 4 + (tg < 2 ? tg : 2);   // 0,5,10,14,18,22,26,30
  const int cnt = 4 + (tg < 2 ? 1 : 0);           // 5,5,4,4,4,4,4,4
  const int row0 = rg * 256 + w * 32 + b;
  const int rb0 = rg * 8 + w;      // 32-row frag-block index

  int tidn0 = task_id[row0];

  // prologue: stage A(start): 9 x 8KB
  {
    const bf16* wb0 = wstream + (size_t)start * WSTRIDE;
#pragma unroll
    for (int c = 0; c < 9; ++c)
      gload_lds16(wb0 + c * 4096 + tid * 8, shA + c * 4096 + tid * 8);
  }

  // const "1" B-frag for the bias K-augment step
  union { unsigned u[4]; bf16x8 v; } cf;
  cf.u[0] = (l < 32) ? 0x3f80u : 0u;
  cf.u[1] = 0u; cf.u[2] = 0u; cf.u[3] = 0u;

  f32x16 z;
#pragma unroll
  for (int i = 0; i < 16; ++i) z[i] = 0.f;
  f32x16 lat[4] = {z, z, z, z};

  const bf16* sb0 = sf + (size_t)rb0 * 8192 + l * 8;

  auto transition = [&](f32x16* acc, bf16x8* f) {
#pragma unroll
    for (int mt = 0; mt < 4; ++mt) {
      unsigned p[8];
#pragma unroll
      for (int q = 0; q < 4; ++q) {
        p[2 * q]     = pack2(fmaxf(acc[mt][4 * q + 0], 0.f), fmaxf(acc[mt][4 * q + 1], 0.f));
        p[2 * q + 1] = pack2(fmaxf(acc[mt][4 * q + 2], 0.f), fmaxf(acc[mt][4 * q + 3], 0.f));
      }
      pl32swap(p[0], p[2]); pl32swap(p[1], p[3]);
      pl32swap(p[4], p[6]); pl32swap(p[5], p[7]);
      union { unsigned u[4]; bf16x8 v; } e, o;
      e.u[0] = p[0]; e.u[1] = p[1]; e.u[2] = p[2]; e.u[3] = p[3];
      o.u[0] = p[4]; o.u[1] = p[5]; o.u[2] = p[6]; o.u[3] = p[7];
      f[2 * mt] = e.v; f[2 * mt + 1] = o.v;
    }
  };

  for (int t = 0; t < cnt; ++t) {
    const int n = start + t;
    const bf16* wbase = wstream + (size_t)n * WSTRIDE;

    // stage B(n): W2/W3, 9 x 8KB (shB free: WAR-fenced by previous iter barrier)
#pragma unroll
    for (int c = 0; c < 9; ++c)
      gload_lds16(wbase + 36864 + c * 4096 + tid * 8, shB + c * 4096 + tid * 8);

    if (t == 0) {   // wait A(start): the 9 B-ops are younger
      asm volatile("s_waitcnt vmcnt(9)" ::: "memory");
      __builtin_amdgcn_s_barrier();
    }

    f32x16 acc[4] = {z, z, z, z};

    // ---- GEMM1 from shA: 16 data ksteps + const kstep
    bf16x8 s0[4];
#pragma unroll
    for (int i = 0; i < 4; ++i) s0[i] = *(const bf16x8*)(sb0 + i * 512);
#pragma unroll
    for (int ks = 0; ks < 16; ++ks) {
      bf16x8 sv = s0[ks & 3];
      if (ks < 12) s0[ks & 3] = *(const bf16x8*)(sb0 + (ks + 4) * 512);
      __builtin_amdgcn_s_setprio(1);
#pragma unroll
      for (int mt = 0; mt < 4; ++mt) {
        bf16x8 wf = *(const bf16x8*)(shA + ((mt * 17 + ks) << 9) + l * 8);
        acc[mt] = mfma32(wf, sv, acc[mt]);
      }
      __builtin_amdgcn_s_setprio(0);
    }
#pragma unroll
    for (int mt = 0; mt < 4; ++mt) {
      bf16x8 wf = *(const bf16x8*)(shA + ((mt * 17 + 16) << 9) + l * 8);
      acc[mt] = mfma32(wf, cf.v, acc[mt]);
    }

    bf16x8 f2[8];
    transition(acc, f2);

    asm volatile("s_waitcnt vmcnt(0)" ::: "memory");  // B(n) landed
    __builtin_amdgcn_s_barrier();                      // + WAR fence for A restage

    // ---- GEMM2 from shB; stage A(t+1) under it
    if (t + 1 < cnt) {
      const bf16* wnext = wstream + (size_t)(n + 1) * WSTRIDE;
#pragma unroll
      for (int c = 0; c < 9; ++c)
        gload_lds16(wnext + c * 4096 + tid * 8, shA + c * 4096 + tid * 8);
    }
#pragma unroll
    for (int mt = 0; mt < 4; ++mt) acc[mt] = z;
#pragma unroll
    for (int ks = 0; ks < 8; ++ks) {
      __builtin_amdgcn_s_setprio(1);
#pragma unroll
      for (int mt = 0; mt < 4; ++mt) {
        bf16x8 wf = *(const bf16x8*)(shB + ((mt * 9 + ks) << 9) + l * 8);
        acc[mt] = mfma32(wf, f2[ks], acc[mt]);
      }
      __builtin_amdgcn_s_setprio(0);
    }
#pragma unroll
    for (int mt = 0; mt < 4; ++mt) {
      bf16x8 wf = *(const bf16x8*)(shB + ((mt * 9 + 8) << 9) + l * 8);
      acc[mt] = mfma32(wf, cf.v, acc[mt]);
    }

    bf16x8 f3[8];
    transition(acc, f3);

    // ---- GEMM3 from shB
#pragma unroll
    for (int mt = 0; mt < 4; ++mt) acc[mt] = z;
#pragma unroll
    for (int ks = 0; ks < 8; ++ks) {
      __builtin_amdgcn_s_setprio(1);
#pragma unroll
      for (int mt = 0; mt < 4; ++mt) {
        bf16x8 wf = *(const bf16x8*)(shB + ((36 + mt * 9 + ks) << 9) + l * 8);
        acc[mt] = mfma32(wf, f3[ks], acc[mt]);
      }
      __builtin_amdgcn_s_setprio(0);
    }
#pragma unroll
    for (int mt = 0; mt < 4; ++mt) {
      bf16x8 wf = *(const bf16x8*)(shB + ((36 + mt * 9 + 8) << 9) + l * 8);
      acc[mt] = mfma32(wf, cf.v, acc[mt]);
    }

    // ---- epilogue (before the staging wait: overlaps A(t+1) flight)
    float ssq = 0.f, dot = 0.f;
    const float* lgb = langn + (size_t)tidn0 * 128;
#pragma unroll
    for (int mt = 0; mt < 4; ++mt)
#pragma unroll
      for (int q = 0; q < 4; ++q) {
        int c0 = mt * 32 + q * 8 + 4 * hi;
        float4 lg = *(const float4*)(lgb + c0);
        float a0 = acc[mt][4 * q + 0], a1 = acc[mt][4 * q + 1];
        float a2 = acc[mt][4 * q + 2], a3 = acc[mt][4 * q + 3];
        ssq += a0 * a0 + a1 * a1 + a2 * a2 + a3 * a3;
        dot += a0 * lg.x + a1 * lg.y + a2 * lg.z + a3 * lg.w;
      }
    ssq += __shfl_xor(ssq, 32);
    dot += __shfl_xor(dot, 32);
    float inv = rsqrtf(ssq);
    if (l < 32) cs_t[(size_t)row0 * NTASK + n] = dot * inv;
    float pwi = pp_t[(size_t)n * BTOT + row0] * inv;
#pragma unroll
    for (int mt = 0; mt < 4; ++mt) lat[mt] += acc[mt] * pwi;
    if (tidn0 == n) {
#pragma unroll
      for (int mt = 0; mt < 4; ++mt)
#pragma unroll
        for (int q = 0; q < 4; ++q) {
          float4 qv = {acc[mt][4 * q + 0] * inv, acc[mt][4 * q + 1] * inv,
                       acc[mt][4 * q + 2] * inv, acc[mt][4 * q + 3] * inv};
          *(float4*)(out_tgt + (size_t)row0 * 128 + mt * 32 + q * 8 + 4 * hi) = qv;
        }
    }

    asm volatile("s_waitcnt vmcnt(0)" ::: "memory");  // A(t+1) landed
    __builtin_amdgcn_s_barrier();                      // + WAR fence for B restage
  }

  // ---- write f16 partial latent: lat_part[tg][row][128]
  __half* lp = lat_part + ((size_t)tg * BTOT + row0) * 128;
#pragma unroll
  for (int mt = 0; mt < 4; ++mt)
#pragma unroll
    for (int q = 0; q < 4; ++q) {
      int c0 = mt * 32 + q * 8 + 4 * hi;
      union { __half h[4]; uint2 u; } v;
      v.h[0] = __float2half(lat[mt][4 * q + 0]);
      v.h[1] = __float2half(lat[mt][4 * q + 1]);
      v.h[2] = __float2half(lat[mt][4 * q + 2]);
      v.h[3] = __float2half(lat[mt][4 * q + 3]);
      *(uint2*)(lp + c0) = v.u;
    }
}

// ---------------- pass 3: per-row combine (1 wave per row) ----------------

__global__ void __launch_bounds__(256)
pass3_kernel(const float* __restrict__ state, const float* __restrict__ cs_t,
             const __half* __restrict__ lat_part,
             float* __restrict__ out_rep, float* __restrict__ out_ltp,
             float* __restrict__ out_lat) {
  int w = threadIdx.x >> 6, l = threadIdx.x & 63;
  size_t row = (size_t)blockIdx.x * 4 + w;

  // log_softmax(cos*10)
  float c = (l < NTASK) ? cs_t[row * NTASK + l] * 10.0f : -1e30f;
  float cm = c;
#pragma unroll
  for (int mm = 1; mm < 64; mm <<= 1) cm = fmaxf(cm, __shfl_xor(cm, mm));
  float ce = (l < NTASK) ? expf(c - cm) : 0.0f;
  float cs = ce;
#pragma unroll
  for (int mm = 1; mm < 64; mm <<= 1) cs += __shfl_xor(cs, mm);
  if (l < NTASK) out_ltp[row * NTASK + l] = c - cm - logf(cs);

  // latent = sum of 8 f16 task-group partials; lane covers cols {2l, 2l+1}
  float2 lv = {0.f, 0.f};
#pragma unroll
  for (int g = 0; g < 8; ++g) {
    __half2 p = *(const __half2*)(lat_part + ((size_t)g * BTOT + row) * 128 + 2 * l);
    lv.x += __low2float(p);
    lv.y += __high2float(p);
  }
  *(float2*)(out_lat + row * 128 + 2 * l) = lv;
  *(float2*)(out_rep + row * 384 + 256 + 2 * l) = lv;

  // state passthrough
  float4 sv = *(const float4*)(state + row * 256 + l * 4);
  *(float4*)(out_rep + row * 384 + l * 4) = sv;
}

// ---------------- launch ----------------

extern "C" void kernel_launch(void* const* d_in, const int* in_sizes, int n_in,
                              void* d_out, int out_size, void* d_ws, size_t ws_size,
                              hipStream_t stream) {
  (void)in_sizes; (void)n_in; (void)out_size; (void)ws_size;
  const float* state = (const float*)d_in[0];
  const int* task_id = (const int*)d_in[1];
  const float* prior = (const float*)d_in[2];
  const float* W1 = (const float*)d_in[3];
  const float* b1 = (const float*)d_in[4];
  const float* W2 = (const float*)d_in[5];
  const float* b2 = (const float*)d_in[6];
  const float* W3 = (const float*)d_in[7];
  const float* b3 = (const float*)d_in[8];
  const float* lang = (const float*)d_in[9];

  char* ws = (char*)d_ws;
  bf16* wstream  = (bf16*)(ws + 0);           //  5,013,504 B (34 x 144KB)
  bf16* sf       = (bf16*)(ws + 5013504);     //  8,388,608 B
  float* langn   = (float*)(ws + 13402112);   //     17,408 B
  float* pp_t    = (float*)(ws + 13419520);   //  2,228,224 B [34][16384]
  float* cs_t    = (float*)(ws + 15647744);   //  2,228,224 B [16384][34]
  __half* lat_part = (__half*)(ws + 17875968);// 33,554,432 B [8][16384][128] f16
                                              // total 51,430,400 B

  float* out = (float*)d_out;
  float* out_rep = out;                 // [B,384]
  float* out_ltp = out + 6291456;       // [B,34]
  float* out_tgt = out + 6848512;       // [B,128]
  float* out_lat = out + 8945664;       // [B,128]

  prep_all<<<3238, 256, 0, stream>>>(W1, W2, W3, b1, b2, b3, state, wstream, sf);
  prep_langn<<<NTASK, 128, 0, stream>>>(lang, langn);
  prep_pprior<<<4096, 256, 0, stream>>>(prior, pp_t);
  pass1_kernel<<<512, 512, 0, stream>>>(task_id, wstream, sf, langn, pp_t,
                                        cs_t, lat_part, out_tgt);
  pass3_kernel<<<4096, 256, 0, stream>>>(state, cs_t, lat_part,
                                         out_rep, out_ltp, out_lat);
}

// Round 13
// 148.467 us; speedup vs baseline: 1.5090x; 1.0823x over previous
//
#include <hip/hip_runtime.h>
#include <hip/hip_bf16.h>
#include <hip/hip_fp16.h>
#include <cstdint>
#include <cstddef>

typedef __bf16 bf16;
typedef __attribute__((ext_vector_type(8))) __bf16 bf16x8;
typedef __attribute__((ext_vector_type(16))) float f32x16;

static_assert(sizeof(bf16x8) == 16, "bf16x8 must be 16B");

#define NTASK 34
#define BTOT 16384
#define WSTRIDE 73728   // bf16 elems per task: A-part 36864 (72KB), B-part 36864 (72KB)

__device__ __forceinline__ f32x16 mfma32(bf16x8 a, bf16x8 b, f32x16 c) {
  return __builtin_amdgcn_mfma_f32_32x32x16_bf16(a, b, c, 0, 0, 0);
}

__device__ __forceinline__ void gload_lds16(const void* g, void* l) {
  __builtin_amdgcn_global_load_lds((__attribute__((address_space(1))) void*)g,
                                   (__attribute__((address_space(3))) void*)l,
                                   16, 0, 0);
}

__device__ __forceinline__ unsigned pack2(float lo, float hi) {
  union { __bf16 h[2]; unsigned u; } v;
  v.h[0] = (__bf16)lo; v.h[1] = (__bf16)hi;
  return v.u;
}

__device__ __forceinline__ void pl32swap(unsigned &a, unsigned &b) {
  asm volatile("v_permlane32_swap_b32 %0, %1" : "+v"(a), "+v"(b));
}

// ---------------- prep (merged: weights + state frags + pprior) ----------------
// bid [0,1190): weights -> 32x32 A-frag blocks (1KB), per-task stream.
//   A-part [0,36864): W1 blocks mt*17+ks (ks=16 bias row), 68KB (+4KB pad)
//   B-part [36864,73728): W2 blocks mt*9+ks; W3 blocks at +18432
// bid [1190,3238): state -> 32x32 B-frag blocks.
// bid [3238,7334): softmax(prior) -> pp_t[34][B]
__global__ void prep_all(const float* __restrict__ W1, const float* __restrict__ W2,
                         const float* __restrict__ W3, const float* __restrict__ b1,
                         const float* __restrict__ b2, const float* __restrict__ b3,
                         const float* __restrict__ state, const float* __restrict__ prior,
                         bf16* __restrict__ wdst, bf16* __restrict__ sdst,
                         float* __restrict__ ppt) {
  int bid = blockIdx.x;
  if (bid < 1190) {
    int idx = bid * 256 + threadIdx.x;    // 34*140*64 = 304640
    if (idx >= 304640) return;
    int n = idx / (140 * 64);
    int r = idx - n * (140 * 64);
    int bb = r >> 6, l = r & 63;
    const float *W, *bias; int real, mt, ks, Kt;
    size_t off;
    if (bb < 68)       { W = W1; bias = b1; mt = bb / 17; ks = bb - mt * 17; real = 16; Kt = 256;
                         off = (size_t)bb * 512; }
    else if (bb < 104) { W = W2; bias = b2; int t = bb - 68;  mt = t / 9; ks = t - mt * 9; real = 8; Kt = 128;
                         off = 36864 + (size_t)(bb - 68) * 512; }
    else               { W = W3; bias = b3; int t = bb - 104; mt = t / 9; ks = t - mt * 9; real = 8; Kt = 128;
                         off = 36864 + 18432 + (size_t)(bb - 104) * 512; }
    int col = mt * 32 + (l & 31);
    bf16x8 v;
    if (ks < real) {
      int k0 = ks * 16 + ((l >> 5) << 3);
      const float* s = W + ((size_t)n * Kt + k0) * 128 + col;
#pragma unroll
      for (int j = 0; j < 8; ++j) v[j] = (bf16)s[(size_t)j * 128];
    } else {
#pragma unroll
      for (int j = 0; j < 8; ++j) v[j] = (bf16)0.f;
      if (l < 32) v[0] = (bf16)bias[n * 128 + col];
    }
    *(bf16x8*)(wdst + (size_t)n * WSTRIDE + off + l * 8) = v;
  } else if (bid < 3238) {
    int idx = (bid - 1190) * 256 + threadIdx.x;   // 524288 exact
    int rb = idx >> 10;
    int r = idx & 1023;
    int ks = r >> 6;
    int l = r & 63;
    int b = rb * 32 + (l & 31);
    int k0 = ks * 16 + ((l >> 5) << 3);
    const float* s = state + (size_t)b * 256 + k0;
    bf16x8 v;
#pragma unroll
    for (int j = 0; j < 8; ++j) v[j] = (bf16)s[j];
    *(bf16x8*)(sdst + (size_t)(rb * 16 + ks) * 512 + l * 8) = v;
  } else {
    int row = (bid - 3238) * 4 + (threadIdx.x >> 6);
    int lane = threadIdx.x & 63;
    float v = (lane < NTASK) ? prior[(size_t)row * NTASK + lane] : -INFINITY;
    float m = v;
#pragma unroll
    for (int mm = 1; mm < 64; mm <<= 1) m = fmaxf(m, __shfl_xor(m, mm));
    float e = (lane < NTASK) ? expf(v - m) : 0.0f;
    float s = e;
#pragma unroll
    for (int mm = 1; mm < 64; mm <<= 1) s += __shfl_xor(s, mm);
    if (lane < NTASK) ppt[(size_t)lane * BTOT + row] = e / s;
  }
}

__global__ void prep_langn(const float* __restrict__ lang, float* __restrict__ out) {
  __shared__ float red[2];
  int n = blockIdx.x;
  int t = threadIdx.x;                        // 128 threads
  float v = lang[(size_t)n * 128 + t];
  float ss = v * v;
#pragma unroll
  for (int m = 1; m < 64; m <<= 1) ss += __shfl_xor(ss, m);
  if ((t & 63) == 0) red[t >> 6] = ss;
  __syncthreads();
  float s = red[0] + red[1];
  float sc = 1.0f / fmaxf(sqrtf(s), 1e-8f);
  out[(size_t)n * 128 + t] = v * sc;
}

// ---------------- pass 1: task-fused, 2 independent blocks/CU ----------------
// grid = 1024: bid = tg*128 + rg. Block = 4 waves x 32 rows = 128 rows, 256 thr,
// 72KB single LDS buffer -> 2 blocks/CU (phase-diverse). launch_bounds(256,2)
// -> 2 waves/SIMD, 256 unified regs/wave (r12-proven budget, no spill).
// Per task: [W1 in buf] G1 | barrier | stage W2W3 (vmcnt(9) split) G2 G3 |
// issue W1(t+1) | epilogue under flight.

__global__ void __launch_bounds__(256, 2)
pass1_kernel(const int* __restrict__ task_id, const bf16* __restrict__ wstream,
             const bf16* __restrict__ sf, const float* __restrict__ langn,
             const float* __restrict__ pp_t,
             float* __restrict__ cs_t, __half* __restrict__ lat_part,
             float* __restrict__ out_tgt) {
  __shared__ __align__(16) bf16 shW[36864];   // 72KB: W1 phase, then W2|W3

  const int tid = threadIdx.x;
  const int l = tid & 63;
  const int w = tid >> 6;          // wave 0..3
  const int hi = l >> 5;
  const int b = l & 31;
  const int tg = blockIdx.x >> 7;  // task group 0..7
  const int rg = blockIdx.x & 127; // 128-row group
  const int start = tg * 4 + (tg < 2 ? tg : 2);   // 0,5,10,14,18,22,26,30
  const int cnt = 4 + (tg < 2 ? 1 : 0);           // 5,5,4,4,4,4,4,4
  const int row0 = rg * 128 + w * 32 + b;
  const int rb0 = rg * 4 + w;      // 32-row frag-block index

  int tidn0 = task_id[row0];

  // prologue: stage W1(start): 17 x 4KB
  {
    const bf16* wb0 = wstream + (size_t)start * WSTRIDE;
#pragma unroll
    for (int c = 0; c < 17; ++c)
      gload_lds16(wb0 + c * 2048 + tid * 8, shW + c * 2048 + tid * 8);
  }

  // const "1" B-frag for the bias K-augment step
  union { unsigned u[4]; bf16x8 v; } cf;
  cf.u[0] = (l < 32) ? 0x3f80u : 0u;
  cf.u[1] = 0u; cf.u[2] = 0u; cf.u[3] = 0u;

  f32x16 z;
#pragma unroll
  for (int i = 0; i < 16; ++i) z[i] = 0.f;
  f32x16 lat[4] = {z, z, z, z};

  const bf16* sb0 = sf + (size_t)rb0 * 8192 + l * 8;

  auto transition = [&](f32x16* acc, bf16x8* f) {
#pragma unroll
    for (int mt = 0; mt < 4; ++mt) {
      unsigned p[8];
#pragma unroll
      for (int q = 0; q < 4; ++q) {
        p[2 * q]     = pack2(fmaxf(acc[mt][4 * q + 0], 0.f), fmaxf(acc[mt][4 * q + 1], 0.f));
        p[2 * q + 1] = pack2(fmaxf(acc[mt][4 * q + 2], 0.f), fmaxf(acc[mt][4 * q + 3], 0.f));
      }
      pl32swap(p[0], p[2]); pl32swap(p[1], p[3]);
      pl32swap(p[4], p[6]); pl32swap(p[5], p[7]);
      union { unsigned u[4]; bf16x8 v; } e, o;
      e.u[0] = p[0]; e.u[1] = p[1]; e.u[2] = p[2]; e.u[3] = p[3];
      o.u[0] = p[4]; o.u[1] = p[5]; o.u[2] = p[6]; o.u[3] = p[7];
      f[2 * mt] = e.v; f[2 * mt + 1] = o.v;
    }
  };

  for (int t = 0; t < cnt; ++t) {
    const int n = start + t;
    const bf16* wbase = wstream + (size_t)n * WSTRIDE;

    // W1(n) landed (also drains prior epilogue stores)
    asm volatile("s_waitcnt vmcnt(0)" ::: "memory");
    __builtin_amdgcn_s_barrier();

    f32x16 acc[4] = {z, z, z, z};

    // ---- GEMM1 from shW[0,34816): 16 data ksteps + const kstep
    bf16x8 s0[4];
#pragma unroll
    for (int i = 0; i < 4; ++i) s0[i] = *(const bf16x8*)(sb0 + i * 512);
#pragma unroll
    for (int ks = 0; ks < 16; ++ks) {
      bf16x8 sv = s0[ks & 3];
      if (ks < 12) s0[ks & 3] = *(const bf16x8*)(sb0 + (ks + 4) * 512);
      __builtin_amdgcn_s_setprio(1);
#pragma unroll
      for (int mt = 0; mt < 4; ++mt) {
        bf16x8 wf = *(const bf16x8*)(shW + ((mt * 17 + ks) << 9) + l * 8);
        acc[mt] = mfma32(wf, sv, acc[mt]);
      }
      __builtin_amdgcn_s_setprio(0);
    }
#pragma unroll
    for (int mt = 0; mt < 4; ++mt) {
      bf16x8 wf = *(const bf16x8*)(shW + ((mt * 17 + 16) << 9) + l * 8);
      acc[mt] = mfma32(wf, cf.v, acc[mt]);
    }

    __builtin_amdgcn_s_barrier();   // all waves done reading W1 (WAR fence)

    // stage W2|W3(n): 18 x 4KB into the same buffer (W2 = first 9 issues)
#pragma unroll
    for (int c = 0; c < 18; ++c)
      gload_lds16(wbase + 36864 + c * 2048 + tid * 8, shW + c * 2048 + tid * 8);

    bf16x8 f2[8];
    transition(acc, f2);            // VALU under the staging flight

    asm volatile("s_waitcnt vmcnt(9)" ::: "memory");  // W2 landed (W3 in flight)
    __builtin_amdgcn_s_barrier();

    // ---- GEMM2 from shW[0,18432)
#pragma unroll
    for (int mt = 0; mt < 4; ++mt) acc[mt] = z;
#pragma unroll
    for (int ks = 0; ks < 8; ++ks) {
      __builtin_amdgcn_s_setprio(1);
#pragma unroll
      for (int mt = 0; mt < 4; ++mt) {
        bf16x8 wf = *(const bf16x8*)(shW + ((mt * 9 + ks) << 9) + l * 8);
        acc[mt] = mfma32(wf, f2[ks], acc[mt]);
      }
      __builtin_amdgcn_s_setprio(0);
    }
#pragma unroll
    for (int mt = 0; mt < 4; ++mt) {
      bf16x8 wf = *(const bf16x8*)(shW + ((mt * 9 + 8) << 9) + l * 8);
      acc[mt] = mfma32(wf, cf.v, acc[mt]);
    }

    bf16x8 f3[8];
    transition(acc, f3);

    asm volatile("s_waitcnt vmcnt(0)" ::: "memory");  // W3 landed
    __builtin_amdgcn_s_barrier();

    // ---- GEMM3 from shW[18432,36864)
#pragma unroll
    for (int mt = 0; mt < 4; ++mt) acc[mt] = z;
#pragma unroll
    for (int ks = 0; ks < 8; ++ks) {
      __builtin_amdgcn_s_setprio(1);
#pragma unroll
      for (int mt = 0; mt < 4; ++mt) {
        bf16x8 wf = *(const bf16x8*)(shW + ((36 + mt * 9 + ks) << 9) + l * 8);
        acc[mt] = mfma32(wf, f3[ks], acc[mt]);
      }
      __builtin_amdgcn_s_setprio(0);
    }
#pragma unroll
    for (int mt = 0; mt < 4; ++mt) {
      bf16x8 wf = *(const bf16x8*)(shW + ((36 + mt * 9 + 8) << 9) + l * 8);
      acc[mt] = mfma32(wf, cf.v, acc[mt]);
    }

    __builtin_amdgcn_s_barrier();   // G3 LDS reads done (WAR for W1(t+1))

    // issue W1(t+1); epilogue VALU runs under its flight
    if (t + 1 < cnt) {
      const bf16* wnext = wstream + (size_t)(n + 1) * WSTRIDE;
#pragma unroll
      for (int c = 0; c < 17; ++c)
        gload_lds16(wnext + c * 2048 + tid * 8, shW + c * 2048 + tid * 8);
    }

    // ---- epilogue
    float ssq = 0.f, dot = 0.f;
    const float* lgb = langn + (size_t)tidn0 * 128;
#pragma unroll
    for (int mt = 0; mt < 4; ++mt)
#pragma unroll
      for (int q = 0; q < 4; ++q) {
        int c0 = mt * 32 + q * 8 + 4 * hi;
        float4 lg = *(const float4*)(lgb + c0);
        float a0 = acc[mt][4 * q + 0], a1 = acc[mt][4 * q + 1];
        float a2 = acc[mt][4 * q + 2], a3 = acc[mt][4 * q + 3];
        ssq += a0 * a0 + a1 * a1 + a2 * a2 + a3 * a3;
        dot += a0 * lg.x + a1 * lg.y + a2 * lg.z + a3 * lg.w;
      }
    ssq += __shfl_xor(ssq, 32);
    dot += __shfl_xor(dot, 32);
    float inv = rsqrtf(ssq);
    if (l < 32) cs_t[(size_t)row0 * NTASK + n] = dot * inv;
    float pwi = pp_t[(size_t)n * BTOT + row0] * inv;
#pragma unroll
    for (int mt = 0; mt < 4; ++mt) lat[mt] += acc[mt] * pwi;
    if (tidn0 == n) {
#pragma unroll
      for (int mt = 0; mt < 4; ++mt)
#pragma unroll
        for (int q = 0; q < 4; ++q) {
          float4 qv = {acc[mt][4 * q + 0] * inv, acc[mt][4 * q + 1] * inv,
                       acc[mt][4 * q + 2] * inv, acc[mt][4 * q + 3] * inv};
          *(float4*)(out_tgt + (size_t)row0 * 128 + mt * 32 + q * 8 + 4 * hi) = qv;
        }
    }
  }

  // ---- write f16 partial latent: lat_part[tg][row][128]
  __half* lp = lat_part + ((size_t)tg * BTOT + row0) * 128;
#pragma unroll
  for (int mt = 0; mt < 4; ++mt)
#pragma unroll
    for (int q = 0; q < 4; ++q) {
      int c0 = mt * 32 + q * 8 + 4 * hi;
      union { __half h[4]; uint2 u; } v;
      v.h[0] = __float2half(lat[mt][4 * q + 0]);
      v.h[1] = __float2half(lat[mt][4 * q + 1]);
      v.h[2] = __float2half(lat[mt][4 * q + 2]);
      v.h[3] = __float2half(lat[mt][4 * q + 3]);
      *(uint2*)(lp + c0) = v.u;
    }
}

// ---------------- pass 3: per-row combine (1 wave per row) ----------------

__global__ void __launch_bounds__(256)
pass3_kernel(const float* __restrict__ state, const float* __restrict__ cs_t,
             const __half* __restrict__ lat_part,
             float* __restrict__ out_rep, float* __restrict__ out_ltp,
             float* __restrict__ out_lat) {
  int w = threadIdx.x >> 6, l = threadIdx.x & 63;
  size_t row = (size_t)blockIdx.x * 4 + w;

  // log_softmax(cos*10)
  float c = (l < NTASK) ? cs_t[row * NTASK + l] * 10.0f : -1e30f;
  float cm = c;
#pragma unroll
  for (int mm = 1; mm < 64; mm <<= 1) cm = fmaxf(cm, __shfl_xor(cm, mm));
  float ce = (l < NTASK) ? expf(c - cm) : 0.0f;
  float cs = ce;
#pragma unroll
  for (int mm = 1; mm < 64; mm <<= 1) cs += __shfl_xor(cs, mm);
  if (l < NTASK) out_ltp[row * NTASK + l] = c - cm - logf(cs);

  // latent = sum of 8 f16 task-group partials; lane covers cols {2l, 2l+1}
  float2 lv = {0.f, 0.f};
#pragma unroll
  for (int g = 0; g < 8; ++g) {
    __half2 p = *(const __half2*)(lat_part + ((size_t)g * BTOT + row) * 128 + 2 * l);
    lv.x += __low2float(p);
    lv.y += __high2float(p);
  }
  *(float2*)(out_lat + row * 128 + 2 * l) = lv;
  *(float2*)(out_rep + row * 384 + 256 + 2 * l) = lv;

  // state passthrough
  float4 sv = *(const float4*)(state + row * 256 + l * 4);
  *(float4*)(out_rep + row * 384 + l * 4) = sv;
}

// ---------------- launch ----------------

extern "C" void kernel_launch(void* const* d_in, const int* in_sizes, int n_in,
                              void* d_out, int out_size, void* d_ws, size_t ws_size,
                              hipStream_t stream) {
  (void)in_sizes; (void)n_in; (void)out_size; (void)ws_size;
  const float* state = (const float*)d_in[0];
  const int* task_id = (const int*)d_in[1];
  const float* prior = (const float*)d_in[2];
  const float* W1 = (const float*)d_in[3];
  const float* b1 = (const float*)d_in[4];
  const float* W2 = (const float*)d_in[5];
  const float* b2 = (const float*)d_in[6];
  const float* W3 = (const float*)d_in[7];
  const float* b3 = (const float*)d_in[8];
  const float* lang = (const float*)d_in[9];

  char* ws = (char*)d_ws;
  bf16* wstream  = (bf16*)(ws + 0);           //  5,013,504 B (34 x 144KB)
  bf16* sf       = (bf16*)(ws + 5013504);     //  8,388,608 B
  float* langn   = (float*)(ws + 13402112);   //     17,408 B
  float* pp_t    = (float*)(ws + 13419520);   //  2,228,224 B [34][16384]
  float* cs_t    = (float*)(ws + 15647744);   //  2,228,224 B [16384][34]
  __half* lat_part = (__half*)(ws + 17875968);// 33,554,432 B [8][16384][128] f16
                                              // total 51,430,400 B

  float* out = (float*)d_out;
  float* out_rep = out;                 // [B,384]
  float* out_ltp = out + 6291456;       // [B,34]
  float* out_tgt = out + 6848512;       // [B,128]
  float* out_lat = out + 8945664;       // [B,128]

  prep_all<<<7334, 256, 0, stream>>>(W1, W2, W3, b1, b2, b3, state, prior,
                                     wstream, sf, pp_t);
  prep_langn<<<NTASK, 128, 0, stream>>>(lang, langn);
  pass1_kernel<<<1024, 256, 0, stream>>>(task_id, wstream, sf, langn, pp_t,
                                         cs_t, lat_part, out_tgt);
  pass3_kernel<<<4096, 256, 0, stream>>>(state, cs_t, lat_part,
                                         out_rep, out_ltp, out_lat);
}